// Round 2
// baseline (2245.212 us; speedup 1.0000x reference)
//
#include <hip/hip_runtime.h>

typedef unsigned short u16;
typedef unsigned int u32;
typedef __attribute__((ext_vector_type(8))) short bf16x8;
typedef __attribute__((ext_vector_type(4))) float f32x4;

#define GLOBAL_AS __attribute__((address_space(1)))
#define LDS_AS __attribute__((address_space(3)))

__device__ __forceinline__ float b2f(u16 u) {
    union { float f; u32 i; } v; v.i = ((u32)u) << 16; return v.f;
}
__device__ __forceinline__ u16 f2b(float f) {
    union { float f; u32 i; } v; v.f = f;
    u32 i = v.i;
    u32 r = (i + 0x7FFFu + ((i >> 16) & 1u)) >> 16;
    return (u16)r;
}
__device__ __forceinline__ float sigm(float x) { return 1.f / (1.f + expf(-x)); }

// ---------------------------------------------------------------------------
// f32 -> bf16 converter (n must be a multiple of 4)
// ---------------------------------------------------------------------------
__global__ void cvt_k(const float* __restrict__ src, u16* __restrict__ dst, int n4)
{
    int id = blockIdx.x * 256 + threadIdx.x;
    if (id >= n4) return;
    float4 v = ((const float4*)src)[id];
    u32 w0 = (u32)f2b(v.x) | ((u32)f2b(v.y) << 16);
    u32 w1 = (u32)f2b(v.z) | ((u32)f2b(v.w) << 16);
    ((u32*)dst)[id * 2]     = w0;
    ((u32*)dst)[id * 2 + 1] = w1;
}

// ---------------------------------------------------------------------------
// Generic GEMM: C[M,N] = A[M,K] @ W[N,K]^T + bias[N]
// A, W bf16 (raw u16); bias f32 (may be null). Writes Cf (f32) and/or Cb (bf16).
// 128x128 tile, BK=64, 256 threads (4 waves 2x2, each 64x64 via 4x4 16x16x32 MFMA).
// Requires M%128==0, N%128==0, K%64==0.
// REMAP: output row m = t*512+b is written at row (b*28+t)  (for [T,B]->[B,T]).
// ---------------------------------------------------------------------------
template<bool LEAKY, bool REMAP>
__global__ __launch_bounds__(256)
void gemm_bt(const u16* __restrict__ A, const u16* __restrict__ W,
             const float* __restrict__ bias,
             float* __restrict__ Cf, u16* __restrict__ Cb,
             int M, int N, int K)
{
    __shared__ __align__(16) u16 lA[128 * 64];
    __shared__ __align__(16) u16 lB[128 * 64];

    const int tid  = threadIdx.x;
    const int lane = tid & 63;
    const int w    = tid >> 6;
    const int wr   = w >> 1;       // wave row (0..1)
    const int wc   = w & 1;        // wave col (0..1)
    const int m0   = blockIdx.y * 128;
    const int n0   = blockIdx.x * 128;

    const int lrow = lane & 15;    // fragment row/col within 16
    const int kgrp = lane >> 4;    // k-group 0..3

    f32x4 acc[4][4] = {};

    for (int k0 = 0; k0 < K; k0 += 64) {
        #pragma unroll
        for (int s = 0; s < 4; ++s) {
            int seg = w * 4 + s;            // 16 segments of 64 chunks
            int g   = seg * 64 + lane;      // chunk id 0..1023
            int row = g >> 3;               // 8 chunks per 64-elem row
            int kk  = (g & 7) * 8;
            const u16* gA = A + (size_t)(m0 + row) * K + k0 + kk;
            const u16* gB = W + (size_t)(n0 + row) * K + k0 + kk;
            __builtin_amdgcn_global_load_lds((GLOBAL_AS const void*)gA,
                                             (LDS_AS void*)(&lA[seg * 512]), 16, 0, 0);
            __builtin_amdgcn_global_load_lds((GLOBAL_AS const void*)gB,
                                             (LDS_AS void*)(&lB[seg * 512]), 16, 0, 0);
        }
        __syncthreads();
        #pragma unroll
        for (int kk = 0; kk < 64; kk += 32) {
            bf16x8 af[4], bfr[4];
            #pragma unroll
            for (int i = 0; i < 4; ++i) {
                int ar = wr * 64 + i * 16 + lrow;
                af[i]  = *(const bf16x8*)&lA[ar * 64 + kk + kgrp * 8];
                int br = wc * 64 + i * 16 + lrow;
                bfr[i] = *(const bf16x8*)&lB[br * 64 + kk + kgrp * 8];
            }
            #pragma unroll
            for (int mi = 0; mi < 4; ++mi)
                #pragma unroll
                for (int ni = 0; ni < 4; ++ni)
                    acc[mi][ni] = __builtin_amdgcn_mfma_f32_16x16x32_bf16(
                        af[mi], bfr[ni], acc[mi][ni], 0, 0, 0);
        }
        __syncthreads();
    }

    #pragma unroll
    for (int mi = 0; mi < 4; ++mi) {
        #pragma unroll
        for (int ni = 0; ni < 4; ++ni) {
            int gcol = n0 + wc * 64 + ni * 16 + lrow;
            float bv = bias ? bias[gcol] : 0.f;
            #pragma unroll
            for (int r = 0; r < 4; ++r) {
                int grow = m0 + wr * 64 + mi * 16 + kgrp * 4 + r;
                float v = acc[mi][ni][r] + bv;
                if (LEAKY) v = (v >= 0.f) ? v : 0.02f * v;
                size_t oidx;
                if (REMAP) {
                    int bb = grow & 511, tt = grow >> 9;
                    oidx = ((size_t)bb * 28 + tt) * (size_t)N + gcol;
                } else {
                    oidx = (size_t)grow * (size_t)N + gcol;
                }
                if (Cf) Cf[oidx] = v;
                if (Cb) Cb[oidx] = f2b(v);
            }
        }
    }
}

// ---------------------------------------------------------------------------
// Embedding gather from f32 table -> bf16: embedded[t*512+b][:] = emb[x[b][t]]
// also x_last[b] = emb[x[b][len-1]]
// ---------------------------------------------------------------------------
__global__ void embed_k(const int* __restrict__ x, const int* __restrict__ xlens,
                        const float* __restrict__ emb,
                        u16* __restrict__ embedded, u16* __restrict__ x_last)
{
    int id = blockIdx.x * 256 + threadIdx.x;   // over T*B*(E/2) = 28*512*128
    if (id >= 28 * 512 * 128) return;
    int e2 = id & 127;
    int tb = id >> 7;          // t*512 + b
    int b  = tb & 511;
    int t  = tb >> 7 >> 2;     // placeholder (recomputed below)
    t = tb >> 9;
    int tok = x[b * 28 + t];
    const float* src = emb + (size_t)tok * 256 + e2 * 2;
    u32 v = (u32)f2b(src[0]) | ((u32)f2b(src[1]) << 16);
    *(u32*)(embedded + (size_t)tb * 256 + e2 * 2) = v;
    if (t == xlens[b] - 1)
        *(u32*)(x_last + (size_t)b * 256 + e2 * 2) = v;
}

// ---------------------------------------------------------------------------
// GRU gate update. gi (bf16, includes input bias), gh (f32, includes hidden bias).
// h_new = (1-z)*n + z*h_old. Optionally record ctx (encoder, at t=len-1) or
// outs (decoder, bf16 slab pre-offset by t).
// ---------------------------------------------------------------------------
__global__ void gru_gate(const u16* __restrict__ gi, const float* __restrict__ gh,
                         const float* __restrict__ h_old, float* __restrict__ h_new,
                         u16* __restrict__ h_newb,
                         const int* __restrict__ xlens, int t,
                         u16* __restrict__ ctx, u16* __restrict__ outs)
{
    int idx = blockIdx.x * 256 + threadIdx.x;   // b*512 + j
    if (idx >= 512 * 512) return;
    int b = idx >> 9, j = idx & 511;
    int base = b * 1536;
    float ir  = b2f(gi[base + j]);
    float iz  = b2f(gi[base + 512 + j]);
    float in_ = b2f(gi[base + 1024 + j]);
    float hr = gh[base + j], hz = gh[base + 512 + j], hn = gh[base + 1024 + j];
    float r = sigm(ir + hr);
    float z = sigm(iz + hz);
    float n = tanhf(in_ + r * hn);
    float h = (1.f - z) * n + z * h_old[idx];
    h_new[idx]  = h;
    h_newb[idx] = f2b(h);
    if (ctx)  { if (xlens[b] - 1 == t) ctx[b * 1024 + j] = f2b(h); }
    if (outs) outs[idx] = f2b(h);
}

// ---------------------------------------------------------------------------
// Backward-direction context: single GRU step with h0 = 0.
// gi (f32, includes bih_b). bhh = bhh_b (f32). ctx_b = (1-z)*n -> ctx[:, 512:1024]
// ---------------------------------------------------------------------------
__global__ void ctxb_k(const float* __restrict__ gi, const float* __restrict__ bhh,
                       u16* __restrict__ ctx)
{
    int idx = blockIdx.x * 256 + threadIdx.x;
    if (idx >= 512 * 512) return;
    int b = idx >> 9, j = idx & 511;
    int base = b * 1536;
    float r = sigm(gi[base + j] + bhh[j]);
    float z = sigm(gi[base + 512 + j] + bhh[512 + j]);
    float n = tanhf(gi[base + 1024 + j] + r * bhh[1024 + j]);
    ctx[b * 1024 + 512 + j] = f2b((1.f - z) * n);
}

// ---------------------------------------------------------------------------

extern "C" void kernel_launch(void* const* d_in, const int* in_sizes, int n_in,
                              void* d_out, int out_size, void* d_ws, size_t ws_size,
                              hipStream_t stream)
{
    const int*   x      = (const int*)d_in[0];
    const int*   xlens  = (const int*)d_in[1];
    const float* emb    = (const float*)d_in[2];
    const float* Wih_f  = (const float*)d_in[3];
    const float* Whh_f  = (const float*)d_in[4];
    const float* bih_f  = (const float*)d_in[5];
    const float* bhh_f  = (const float*)d_in[6];
    const float* Wih_b  = (const float*)d_in[7];
    const float* bih_b  = (const float*)d_in[9];
    const float* bhh_b  = (const float*)d_in[10];
    const float* fc1_w  = (const float*)d_in[11];
    const float* fc1_b  = (const float*)d_in[12];
    const float* fc2_w  = (const float*)d_in[13];
    const float* fc2_b  = (const float*)d_in[14];
    const float* dWih   = (const float*)d_in[15];
    const float* dWhh   = (const float*)d_in[16];
    const float* dbih   = (const float*)d_in[17];
    const float* dbhh   = (const float*)d_in[18];
    const float* re_w   = (const float*)d_in[19];
    const float* re_b   = (const float*)d_in[20];
    const float* hv_w   = (const float*)d_in[21];
    const float* hv_b   = (const float*)d_in[22];

    float* out        = (float*)d_out;
    float* out_logits = out;                                   // [28,512,32000] f32
    float* out_z      = out + (size_t)28 * 512 * 32000;        // [512,128] f32
    float* out_re     = out_z + 512 * 128;                     // [512,28,256] f32

    // --- ws sub-allocator (bf16 weights + small scratch), ~66 MB ---
    char* ws = (char*)d_ws;
    size_t off = 0;
    auto alloc = [&](size_t bytes) -> void* {
        void* p = ws + off; off += (bytes + 255) & ~(size_t)255; return p;
    };
    u16* wWihf = (u16*)alloc(1536 * 256 * 2);
    u16* wWhhf = (u16*)alloc(1536 * 512 * 2);
    u16* wWihb = (u16*)alloc(1536 * 256 * 2);
    u16* wfc1  = (u16*)alloc(128 * 1024 * 2);
    u16* wfc2  = (u16*)alloc(512 * 128 * 2);
    u16* wdWih = (u16*)alloc(1536 * 512 * 2);
    u16* wdWhh = (u16*)alloc(1536 * 512 * 2);
    u16* wre   = (u16*)alloc(256 * 512 * 2);
    u16* whv   = (u16*)alloc((size_t)32000 * 512 * 2);
    float* gh     = (float*)alloc(512 * 1536 * 4);
    float* hf     = (float*)alloc(512 * 512 * 4);
    u16*   hb     = (u16*)  alloc(512 * 512 * 2);
    u16*   ctx    = (u16*)  alloc(512 * 1024 * 2);
    float* gi_bw  = (float*)alloc(512 * 1536 * 4);
    float* out0f  = (float*)alloc(512 * 512 * 4);
    u16*   out0b  = (u16*)  alloc(512 * 512 * 2);
    u16*   out_zb = (u16*)  alloc(512 * 128 * 2);
    u16*   gi_dec = (u16*)  alloc(512 * 1536 * 2);
    u16*   outsb  = (u16*)  alloc((size_t)28 * 512 * 512 * 2);

    // --- big transient scratch overlaid into the logits region of d_out
    //     (dead before step 10 overwrites it) ---
    char* ds = (char*)d_out;
    size_t doff = 0;
    auto dalloc = [&](size_t bytes) -> void* {
        void* p = ds + doff; doff += (bytes + 255) & ~(size_t)255; return p;
    };
    u16* embedded = (u16*)dalloc((size_t)28 * 512 * 256 * 2);   // 7.3 MB
    u16* x_last   = (u16*)dalloc(512 * 256 * 2);
    u16* gi_f     = (u16*)dalloc((size_t)28 * 512 * 1536 * 2);  // 44 MB

    // 0. weight conversion f32 -> bf16
    auto cvt = [&](const float* s, u16* d, int n) {
        cvt_k<<<(n / 4 + 255) / 256, 256, 0, stream>>>(s, d, n / 4);
    };
    cvt(Wih_f, wWihf, 1536 * 256);
    cvt(Whh_f, wWhhf, 1536 * 512);
    cvt(Wih_b, wWihb, 1536 * 256);
    cvt(fc1_w, wfc1, 128 * 1024);
    cvt(fc2_w, wfc2, 512 * 128);
    cvt(dWih, wdWih, 1536 * 512);
    cvt(dWhh, wdWhh, 1536 * 512);
    cvt(re_w, wre, 256 * 512);
    cvt(hv_w, whv, 32000 * 512);

    // 1. embedding gather (+ last valid token)
    embed_k<<<7168, 256, 0, stream>>>(x, xlens, emb, embedded, x_last);

    // 2. encoder input-side gates for all timesteps: gi_f = embedded @ Wih_f^T + bih_f
    gemm_bt<false, false><<<dim3(12, 112), 256, 0, stream>>>(
        embedded, wWihf, bih_f, nullptr, gi_f, 14336, 1536, 256);

    // 3. forward encoder scan (h0 = 0)
    hipMemsetAsync(hf, 0, 512 * 512 * 4, stream);
    hipMemsetAsync(hb, 0, 512 * 512 * 2, stream);
    for (int t = 0; t < 28; ++t) {
        gemm_bt<false, false><<<dim3(12, 4), 256, 0, stream>>>(
            hb, wWhhf, bhh_f, gh, nullptr, 512, 1536, 512);
        gru_gate<<<1024, 256, 0, stream>>>(
            gi_f + (size_t)t * 512 * 1536, gh, hf, hf, hb, xlens, t, ctx, nullptr);
    }

    // 4. backward-direction context = one GRU step on last token, h0 = 0
    gemm_bt<false, false><<<dim3(12, 4), 256, 0, stream>>>(
        x_last, wWihb, bih_b, gi_bw, nullptr, 512, 1536, 256);
    ctxb_k<<<1024, 256, 0, stream>>>(gi_bw, bhh_b, ctx);

    // 5. z = context @ fc1_w^T + fc1_b  (f32 to d_out, bf16 copy for next GEMM)
    gemm_bt<false, false><<<dim3(1, 4), 256, 0, stream>>>(
        ctx, wfc1, fc1_b, out_z, out_zb, 512, 128, 1024);

    // 6. out0 = z @ fc2_w^T + fc2_b
    gemm_bt<false, false><<<dim3(4, 4), 256, 0, stream>>>(
        out_zb, wfc2, fc2_b, out0f, out0b, 512, 512, 128);

    // 7. decoder constant input gates: gi_dec = out0 @ dec_Wih^T + dec_bih
    gemm_bt<false, false><<<dim3(12, 4), 256, 0, stream>>>(
        out0b, wdWih, dbih, nullptr, gi_dec, 512, 1536, 512);

    // 8. decoder scan (h0 = out0), record outs
    for (int t = 0; t < 28; ++t) {
        const u16*   a    = (t == 0) ? out0b : hb;
        const float* hold = (t == 0) ? out0f : hf;
        gemm_bt<false, false><<<dim3(12, 4), 256, 0, stream>>>(
            a, wdWhh, dbhh, gh, nullptr, 512, 1536, 512);
        gru_gate<<<1024, 256, 0, stream>>>(
            gi_dec, gh, hold, hf, hb, nullptr, t, nullptr,
            outsb + (size_t)t * 512 * 512);
    }

    // 9. re_emb = leakyrelu(outs @ re_w^T + re_b), scattered [T,B]->[B,T]
    gemm_bt<true, true><<<dim3(2, 112), 256, 0, stream>>>(
        outsb, wre, re_b, out_re, nullptr, 14336, 256, 512);

    // 10. logits = outs @ hv_w^T + hv_b   [T,B,V]  (overwrites d_out scratch)
    gemm_bt<false, false><<<dim3(250, 112), 256, 0, stream>>>(
        outsb, whv, hv_b, out_logits, nullptr, 14336, 32000, 512);
}